// Round 1
// baseline (116.985 us; speedup 1.0000x reference)
//
#include <hip/hip_runtime.h>
#include <math.h>

#define BB 16
#define CC 256
#define HH 64
#define WW 32
#define NN (HH*WW)            // 2048
#define NEGC (-9e15f)

// scratch as module-scope device globals (capture-safe, no dependence on ws_size)
__device__ float g_g[BB*CC];          // adjacent-channel dots, g[b][c] = <x[b,c], x[b,c+1]>
__device__ float g_wlo[BB*CC];        // channel-softmax weight on c-1
__device__ float g_whi[BB*CC];        // channel-softmax weight on c+1
__device__ float g_Wt[CC*64];         // BN-folded transposed weights: Wt[c][k], k<32 alpha, k>=32 sigma
__device__ float g_bias[64];          // BN-folded bias
__device__ float g_as[(size_t)BB*NN*64];  // as[b][p][k]: alpha (0..31), sigma (32..63)

// ---------------- K1: adjacent-channel dot products ----------------
__global__ __launch_bounds__(256) void k_g(const float* __restrict__ x) {
    int blk = blockIdx.x;
    int b = blk / (CC-1);
    int c = blk - b*(CC-1);
    const float4* r0 = (const float4*)(x + ((size_t)b*CC + c)*NN);
    const float4* r1 = (const float4*)(x + ((size_t)b*CC + c + 1)*NN);
    int t = threadIdx.x;
    float4 a0 = r0[t],      b0 = r1[t];
    float4 a1 = r0[t+256],  b1 = r1[t+256];
    float s = a0.x*b0.x + a0.y*b0.y + a0.z*b0.z + a0.w*b0.w
            + a1.x*b1.x + a1.y*b1.y + a1.z*b1.z + a1.w*b1.w;
    #pragma unroll
    for (int off = 32; off > 0; off >>= 1) s += __shfl_down(s, off, 64);
    __shared__ float red[4];
    if ((t & 63) == 0) red[t >> 6] = s;
    __syncthreads();
    if (t == 0) g_g[b*CC + c] = red[0] + red[1] + red[2] + red[3];
}

// ---------------- K2: prep (BN-folded Wt/bias; channel pair softmax) ----------------
__global__ __launch_bounds__(256) void k_prep(
        const float* __restrict__ wa, const float* __restrict__ ga,
        const float* __restrict__ ba, const float* __restrict__ ma,
        const float* __restrict__ va, const float* __restrict__ wsig,
        const float* __restrict__ gs, const float* __restrict__ bs,
        const float* __restrict__ ms, const float* __restrict__ vs) {
    int t = threadIdx.x;
    if (blockIdx.x == 0) {
        // t = channel c
        #pragma unroll 4
        for (int k = 0; k < 64; ++k) {
            float inv, w;
            if (k < 32) { inv = ga[k] * rsqrtf(va[k] + 1e-5f); w = wa[k*CC + t]; }
            else { int kk = k - 32; inv = gs[kk] * rsqrtf(vs[kk] + 1e-5f); w = wsig[kk*CC + t]; }
            g_Wt[t*64 + k] = w * inv;
        }
        if (t < 64) {
            float inv, bb, mm;
            if (t < 32) { inv = ga[t] * rsqrtf(va[t] + 1e-5f); bb = ba[t]; mm = ma[t]; }
            else { int kk = t - 32; inv = gs[kk] * rsqrtf(vs[kk] + 1e-5f); bb = bs[kk]; mm = ms[kk]; }
            g_bias[t] = bb - mm * inv;
        }
    } else {
        int b = blockIdx.x - 1;
        int c = t;
        float glo = (c > 0)      ? g_g[b*CC + c - 1] : NEGC;
        float ghi = (c < CC - 1) ? g_g[b*CC + c]     : NEGC;
        float m = fmaxf(glo, ghi);
        float elo = expf(glo - m), ehi = expf(ghi - m);
        float inv = 1.0f / (elo + ehi);
        g_wlo[b*CC + c] = elo * inv;
        g_whi[b*CC + c] = ehi * inv;
    }
}

// ---------------- K3: alpha/sigma 1x1-conv GEMM, position-major output ----------------
// as[b][p][k] = relu(bias[k] + sum_c Wt[c][k] * x[b][c][p])
// grid: B*32 blocks; 256 threads = 64 positions x 4 k-groups of 16
__global__ __launch_bounds__(256) void k_gemm(const float* __restrict__ x) {
    int blk = blockIdx.x;
    int b = blk >> 5;
    int tile = blk & 31;
    int t = threadIdx.x;
    int p = (tile << 6) + (t & 63);
    int kg = __builtin_amdgcn_readfirstlane(t >> 6);  // wave-uniform k-group
    const float* xp = x + (size_t)b*CC*NN + p;
    const float* wt = g_Wt + kg*16;
    float acc[16];
    #pragma unroll
    for (int i = 0; i < 16; ++i) acc[i] = 0.f;
    #pragma unroll 4
    for (int c = 0; c < CC; ++c) {
        float xv = xp[(size_t)c*NN];
        #pragma unroll
        for (int i = 0; i < 16; ++i)
            acc[i] = fmaf(wt[c*64 + i], xv, acc[i]);   // wt reads are wave-uniform -> s_load
    }
    int kb = kg*16;
    float* o = g_as + (((size_t)b*NN + p) << 6) + kb;
    #pragma unroll
    for (int i = 0; i < 16; ++i)
        o[i] = fmaxf(acc[i] + g_bias[kb + i], 0.f);
}

// ---------------- K4: attention weights + stencil + channel blend + elu + mix ----------------
// grid: 256 blocks = b(16) x strip(8 rows x 32 cols)(8) x channel-half(2); 256 threads
__global__ __launch_bounds__(256) void k_main(const float* __restrict__ x,
                                              const float* __restrict__ gama_p,
                                              float* __restrict__ out) {
    __shared__ float wtab[256][9];   // 8 softmax weights per position (+pad)
    int blk = blockIdx.x;
    int b = blk >> 4;
    int strip = (blk >> 1) & 7;
    int chalf = blk & 1;
    int t = threadIdx.x;
    int r0 = strip << 3;

    // ---- step 1: per-position masked softmax over 8 neighbor dots ----
    {
        int row = t >> 5, col = t & 31;
        int gr = r0 + row;
        int p = gr*WW + col;
        const float4* ap = (const float4*)(g_as + (((size_t)b*NN + p) << 6));
        float a[32];
        #pragma unroll
        for (int k4 = 0; k4 < 8; ++k4) {
            float4 v = ap[k4];
            a[4*k4+0] = v.x; a[4*k4+1] = v.y; a[4*k4+2] = v.z; a[4*k4+3] = v.w;
        }
        const int dy[8] = {-1,-1,-1, 0,0, 1,1,1};
        const int dx[8] = {-1, 0, 1,-1,1,-1,0,1};
        float logit[8];
        float m = -3.0e38f;
        #pragma unroll
        for (int j = 0; j < 8; ++j) {
            int qr = gr + dy[j], qc = col + dx[j];
            bool ok = (qr >= 0) && (qr < HH) && (qc >= 0) && (qc < WW);
            int q = ok ? (qr*WW + qc) : p;
            const float4* sp = (const float4*)(g_as + (((size_t)b*NN + q) << 6) + 32);
            float d = 0.f;
            #pragma unroll
            for (int k4 = 0; k4 < 8; ++k4) {
                float4 s4 = sp[k4];
                d = fmaf(a[4*k4+0], s4.x, d);
                d = fmaf(a[4*k4+1], s4.y, d);
                d = fmaf(a[4*k4+2], s4.z, d);
                d = fmaf(a[4*k4+3], s4.w, d);
            }
            logit[j] = ok ? d : NEGC;
            m = fmaxf(m, logit[j]);
        }
        float sum = 0.f;
        float e[8];
        #pragma unroll
        for (int j = 0; j < 8; ++j) { e[j] = expf(logit[j] - m); sum += e[j]; }
        float inv = 1.0f / sum;
        #pragma unroll
        for (int j = 0; j < 8; ++j) wtab[t][j] = e[j] * inv;
    }
    __syncthreads();

    // ---- step 2: stencil over 32 channels per wave ----
    int wave = __builtin_amdgcn_readfirstlane(t >> 6);
    int lane = t & 63;
    int lrow = lane >> 3;            // row within strip
    int lcq  = (lane & 7) << 2;      // column quad start
    float wq[4][8];                  // channel-invariant weights, hoisted to registers
    #pragma unroll
    for (int i = 0; i < 4; ++i) {
        int prow = lrow*32 + lcq + i;
        #pragma unroll
        for (int j = 0; j < 8; ++j) wq[i][j] = wtab[prow][j];
    }
    float gama = gama_p[0];
    int c0 = chalf*128 + wave*32;
    int pbase = r0*WW + lane*4;      // strip positions are contiguous
    const float* xb = x + (size_t)b*CC*NN;
    float* ob = out + (size_t)b*CC*NN;
    int grow = r0 + lrow;
    int offA = (grow > 0)      ? (pbase - WW) : pbase;  // clamped; masked weights anyway
    int offB = (grow < HH - 1) ? (pbase + WW) : pbase;

    float pm1[4], o0[4];
    {
        int cm1 = (c0 > 0) ? c0 - 1 : 0;              // wlo==0 at c==0
        float4 v = *(const float4*)(xb + (size_t)cm1*NN + pbase);
        pm1[0]=v.x; pm1[1]=v.y; pm1[2]=v.z; pm1[3]=v.w;
        float4 w = *(const float4*)(xb + (size_t)c0*NN + pbase);
        o0[0]=w.x; o0[1]=w.y; o0[2]=w.z; o0[3]=w.w;
    }
    for (int c = c0; c < c0 + 32; ++c) {
        int cp1 = (c < CC-1) ? c + 1 : CC-1;          // whi==0 at c==C-1
        float4 v1 = *(const float4*)(xb + (size_t)cp1*NN + pbase);
        float p1[4] = {v1.x, v1.y, v1.z, v1.w};
        float4 va4 = *(const float4*)(xb + (size_t)c*NN + offA);
        float aw[4] = {va4.x, va4.y, va4.z, va4.w};
        float4 vb4 = *(const float4*)(xb + (size_t)c*NN + offB);
        float bw[4] = {vb4.x, vb4.y, vb4.z, vb4.w};
        float al  = __shfl_up(aw[3], 1);
        float ar  = __shfl_down(aw[0], 1);
        float ol  = __shfl_up(o0[3], 1);
        float orr = __shfl_down(o0[0], 1);
        float bl  = __shfl_up(bw[3], 1);
        float br  = __shfl_down(bw[0], 1);
        float wlo_c = g_wlo[b*CC + c];
        float whi_c = g_whi[b*CC + c];
        float res[4];
        #pragma unroll
        for (int i = 0; i < 4; ++i) {
            float ul = (i == 0) ? al  : aw[i-1];
            float uu = aw[i];
            float ur = (i == 3) ? ar  : aw[i+1];
            float ll = (i == 0) ? ol  : o0[i-1];
            float rr = (i == 3) ? orr : o0[i+1];
            float dl = (i == 0) ? bl  : bw[i-1];
            float dd = bw[i];
            float dr = (i == 3) ? br  : bw[i+1];
            float hs = wq[i][0]*ul + wq[i][1]*uu + wq[i][2]*ur
                     + wq[i][3]*ll + wq[i][4]*rr
                     + wq[i][5]*dl + wq[i][6]*dd + wq[i][7]*dr;
            float hp = wlo_c*pm1[i] + whi_c*p1[i];
            float h  = hs + hp;
            float el = (h > 0.f) ? h : expm1f(h);
            res[i] = o0[i] + gama*(el - o0[i]);       // (1-g)x + g*h'
        }
        *(float4*)(ob + (size_t)c*NN + pbase) = make_float4(res[0], res[1], res[2], res[3]);
        #pragma unroll
        for (int i = 0; i < 4; ++i) { pm1[i] = o0[i]; o0[i] = p1[i]; }
    }
}

extern "C" void kernel_launch(void* const* d_in, const int* in_sizes, int n_in,
                              void* d_out, int out_size, void* d_ws, size_t ws_size,
                              hipStream_t stream) {
    const float* x    = (const float*)d_in[0];
    const float* wa   = (const float*)d_in[1];
    const float* ga   = (const float*)d_in[2];
    const float* ba   = (const float*)d_in[3];
    const float* ma   = (const float*)d_in[4];
    const float* va   = (const float*)d_in[5];
    const float* wsig = (const float*)d_in[6];
    const float* gs   = (const float*)d_in[7];
    const float* bs   = (const float*)d_in[8];
    const float* ms   = (const float*)d_in[9];
    const float* vs   = (const float*)d_in[10];
    const float* gama = (const float*)d_in[11];
    float* out = (float*)d_out;

    hipLaunchKernelGGL(k_g,    dim3(BB*(CC-1)), dim3(256), 0, stream, x);
    hipLaunchKernelGGL(k_prep, dim3(BB+1),      dim3(256), 0, stream,
                       wa, ga, ba, ma, va, wsig, gs, bs, ms, vs);
    hipLaunchKernelGGL(k_gemm, dim3(BB*32),     dim3(256), 0, stream, x);
    hipLaunchKernelGGL(k_main, dim3(256),       dim3(256), 0, stream, x, gama, out);
}